// Round 1
// baseline (248.628 us; speedup 1.0000x reference)
//
#include <hip/hip_runtime.h>

// GetWeightMatrix: weight = 1 + 1.5 * sum_{5x5 shifts}(y_pad != argmax_c(x))
// x: [8, 21, 512, 512] f32, y: [8, 512, 512] i32, out: [8, 1, 512, 512] f32
// Memory-bound on x (176 MB of 193 MB total). One thread = 4 h-pixels (float4).

constexpr int B = 8;
constexpr int C = 21;
constexpr int W = 512;
constexpr int H = 512;
constexpr int PIX = W * H;

__global__ __launch_bounds__(256) void getweight_kernel(
    const float* __restrict__ x, const int* __restrict__ y,
    float* __restrict__ out)
{
    const int tid = blockIdx.x * blockDim.x + threadIdx.x;
    const int gpr = H / 4;        // 128 float4-groups per row
    const int gpi = W * gpr;      // 65536 groups per image
    const int b   = tid / gpi;
    const int rem = tid - b * gpi;
    const int w   = rem / gpr;
    const int h   = (rem - w * gpr) << 2;   // base h of this thread's 4 pixels

    // ---- argmax over 21 channels, 4 pixels at once (float4 strided loads) ----
    const float* xp = x + (size_t)b * C * PIX + (size_t)w * H + h;
    float4 best = *reinterpret_cast<const float4*>(xp);
    int am0 = 0, am1 = 0, am2 = 0, am3 = 0;
#pragma unroll
    for (int c = 1; c < C; ++c) {
        float4 v = *reinterpret_cast<const float4*>(xp + (size_t)c * PIX);
        // strict > keeps the FIRST max index, matching jnp.argmax tie-break
        if (v.x > best.x) { best.x = v.x; am0 = c; }
        if (v.y > best.y) { best.y = v.y; am1 = c; }
        if (v.z > best.z) { best.z = v.z; am2 = c; }
        if (v.w > best.w) { best.w = v.w; am3 = c; }
    }
    const int xm[4] = {am0, am1, am2, am3};

    // ---- 5x5 neighborhood mismatch count vs y (zero-padded => OOB label 0) ----
    const int* yb = y + b * PIX;
    int cnt[4] = {0, 0, 0, 0};
#pragma unroll
    for (int di = 0; di < 5; ++di) {
        const int ww = w + di - 2;
        const bool wok = (unsigned)ww < (unsigned)W;
        int yr[8];  // y row values covering h-2 .. h+5 (all 4 pixels x 5 dj)
#pragma unroll
        for (int k = 0; k < 8; ++k) {
            const int hh = h + k - 2;
            const bool ok = wok && ((unsigned)hh < (unsigned)H);
            yr[k] = ok ? yb[ww * H + hh] : 0;   // pad value = class 0
        }
#pragma unroll
        for (int j = 0; j < 4; ++j) {
#pragma unroll
            for (int dj = 0; dj < 5; ++dj) {
                cnt[j] += (yr[j + dj] != xm[j]) ? 1 : 0;
            }
        }
    }

    float4 res;
    res.x = 1.0f + 1.5f * (float)cnt[0];
    res.y = 1.0f + 1.5f * (float)cnt[1];
    res.z = 1.0f + 1.5f * (float)cnt[2];
    res.w = 1.0f + 1.5f * (float)cnt[3];
    *reinterpret_cast<float4*>(out + (size_t)b * PIX + (size_t)w * H + h) = res;
}

extern "C" void kernel_launch(void* const* d_in, const int* in_sizes, int n_in,
                              void* d_out, int out_size, void* d_ws, size_t ws_size,
                              hipStream_t stream) {
    const float* x = (const float*)d_in[0];   // [8,21,512,512] f32
    const int*   y = (const int*)d_in[1];     // [8,512,512] i32
    float* out = (float*)d_out;               // [8,1,512,512] f32

    const int total_threads = B * PIX / 4;    // 524288
    const int block = 256;
    const int grid = total_threads / block;   // 2048
    getweight_kernel<<<grid, block, 0, stream>>>(x, y, out);
}